// Round 2
// baseline (6860.322 us; speedup 1.0000x reference)
//
#include <hip/hip_runtime.h>
#include <hip/hip_bf16.h>
#include <hip/hip_cooperative_groups.h>
#include <cmath>

namespace cg = cooperative_groups;

using bf16 = __hip_bfloat16;

#define DEV static __device__ __forceinline__

DEV float toF(float x) { return x; }
DEV float toF(bf16 x) { return __bfloat162float(x); }

// dual-dtype load: f32==1 -> buffer is float, else bf16
DEV float loadF(const void* p, long i, int f32) {
    return f32 ? ((const float*)p)[i] : toF(((const bf16*)p)[i]);
}
DEV void storeOut(void* out, long i, float v, int f32) {
    if (f32) ((float*)out)[i] = v;
    else ((bf16*)out)[i] = __float2bfloat16(v);
}

__device__ __constant__ float kLOG2PI = 1.8378770664093453f;
DEV float sigf(float x) { return 1.0f / (1.0f + __expf(-x)); }

typedef __attribute__((ext_vector_type(4))) float fx4;
typedef __attribute__((ext_vector_type(8))) short s16x8;   // 8 bf16 (4 VGPR)

// ---------------- workspace layout (bytes), peak 30,485,248 (~29.1 MB) ------
static constexpr size_t OFF_WIHT  = 0;          // bf16 [518][2048]
static constexpr size_t OFF_WHHT  = 2121728;    // bf16 [512][2048]
static constexpr size_t OFF_BSUM  = 4218880;    // f32 2048
static constexpr size_t OFF_LINB  = 4227072;    // f32 512
static constexpr size_t OFF_HB    = 4229120;    // f32 1024
static constexpr size_t OFF_HT0   = 4233216;    // bf16 h0b [128][512] (131072 B used)
static constexpr size_t OFF_HT1   = 4495360;    // (free)
static constexpr size_t OFF_CT    = 4757504;    // f32 [512][128]
static constexpr size_t OFF_CW1   = 5019648;    // bf16 6144
static constexpr size_t OFF_CW2   = 5031936;    // bf16 32768
static constexpr size_t OFF_CW3   = 5097472;    // bf16 36864
static constexpr size_t OFF_CBIAS = 5171200;    // f32 160
static constexpr size_t OFF_ACT   = 5171840;    // bf16 24576
static constexpr size_t OFF_FB    = 5220992;    // f32 8
static constexpr size_t OFF_FLAG  = 5221024;    // int (padded)
static constexpr size_t OFF_XIN   = 5221120;    // bf16 [8192][518] (later t1 bf16)
static constexpr size_t OFF_C3H   = 13708032;   // CNN scratch / zx chunk / t2
static constexpr size_t OFF_HID   = 22096640;   // CNN out1 scratch, then bf16 [8192][512]
// CNN-phase aliases inside the (then unused) C3H / HID regions:
static constexpr size_t OFF_OUT2 = OFF_C3H;               // bf16 [512][6][6][64]  = 2,359,296
static constexpr size_t OFF_OUT3 = OFF_C3H + 2359296;     // bf16 [512][1024]      = 1,048,576
static constexpr size_t OFF_LINW = OFF_C3H + 3407872;     // bf16 [1024][512]      = 1,048,576
static constexpr size_t OFF_OUT1 = OFF_HID;               // bf16 [512][15][15][32]= 7,372,800
// end 30,485,248

// ================= dtype detector =================
__global__ void detect_k(const void* __restrict__ action, int* __restrict__ flag) {
    int lane = threadIdx.x;                        // 64 lanes
    const unsigned short* p = (const unsigned short*)action;
    unsigned short v = p[lane];
    int e = (v >> 7) & 0xFF;                       // bf16 exponent field
    bool bad = (e >= 0x8C);                        // |x| >= 2^13 impossible for N(0,1) bf16
    unsigned long long m = __ballot(bad);
    if (lane == 0) *flag = (m != 0ull) ? 1 : 0;    // bad pattern -> data is f32
}

// ================= prep: canonicalize everything small =================
__global__ __launch_bounds__(256) void prep_k(
    const void* w_ih, const void* w_hh, const void* b_ih, const void* b_hh,
    const void* lin_b, const void* ab1, const void* ab2, const void* cb1, const void* cb2,
    const void* h0, const void* c0,
    const void* c1w, const void* c2w, const void* c3w,
    const void* c1b, const void* c2b, const void* c3b,
    const void* action, const void* ab3, const void* cb3, const void* logstd,
    bf16* __restrict__ wihT, bf16* __restrict__ whhT,
    float* __restrict__ bsum, float* __restrict__ linbf, float* __restrict__ hbias,
    bf16* __restrict__ h0b, float* __restrict__ cT,
    bf16* __restrict__ cw1, bf16* __restrict__ cw2, bf16* __restrict__ cw3,
    float* __restrict__ cbias, bf16* __restrict__ act, float* __restrict__ fb,
    const int* __restrict__ flagp,
    const void* lin_w, bf16* __restrict__ linwb)
{
    const int f = *flagp;
    long i = (long)blockIdx.x * 256 + threadIdx.x;
    if (i < 1060864) { long k = i >> 11, j = i & 2047;
        wihT[i] = __float2bfloat16(loadF(w_ih, j * 518 + k, f)); return; }
    i -= 1060864;
    if (i < 1048576) { long k = i >> 11, j = i & 2047;
        whhT[i] = __float2bfloat16(loadF(w_hh, j * 512 + k, f)); return; }
    i -= 1048576;
    if (i < 2048) { bsum[i] = loadF(b_ih, i, f) + loadF(b_hh, i, f); return; }
    i -= 2048;
    if (i < 512)  { linbf[i] = loadF(lin_b, i, f); return; }
    i -= 512;
    if (i < 1024) { int w = (int)(i >> 8), r = (int)(i & 255);
        const void* s = (w == 0) ? ab1 : (w == 1) ? ab2 : (w == 2) ? cb1 : cb2;
        hbias[i] = loadF(s, r, f); return; }
    i -= 1024;
    if (i < 65536) { h0b[i] = __float2bfloat16(loadF(h0, i, f)); return; }  // [128][512] row-major
    i -= 65536;
    if (i < 65536) { long b = i & 127, k = i >> 7; cT[i]  = loadF(c0, b * 512 + k, f); return; }
    i -= 65536;
    if (i < 6144)  { cw1[i] = __float2bfloat16(loadF(c1w, i, f)); return; }
    i -= 6144;
    if (i < 32768) { cw2[i] = __float2bfloat16(loadF(c2w, i, f)); return; }
    i -= 32768;
    if (i < 36864) { cw3[i] = __float2bfloat16(loadF(c3w, i, f)); return; }
    i -= 36864;
    if (i < 160) { float v = (i < 32) ? loadF(c1b, i, f)
                         : (i < 96) ? loadF(c2b, i - 32, f) : loadF(c3b, i - 96, f);
        cbias[i] = v; return; }
    i -= 160;
    if (i < 24576) { act[i] = __float2bfloat16(loadF(action, i, f)); return; }
    i -= 24576;
    if (i < 8) {
        float v = 0.f;
        if (i < 3) v = loadF(ab3, i, f);
        else if (i == 3) v = loadF(cb3, 0, f);
        else if (i < 7) v = loadF(logstd, i - 4, f);
        fb[i] = v; return;
    }
    i -= 8;
    if (i < 524288) { linwb[i] = __float2bfloat16(loadF(lin_w, i, f)); return; }
}

// ================= MFMA implicit GEMM =================
// C[M][N] = ACT(A @ B + bias), bf16 storage, f32 accum on matrix cores.
// MODE 0: A is plain bf16 row-major [M][lda]. MODE 1: A is conv input (dual
// dtype via flag, NHWC, img offset by imgBase). MODE 2: conv input, bf16.
// BSRC 0: B is bf16 [K][ldb]. BSRC 1: B is dual-dtype raw input via flag.
// ACT: 0 none, 1 relu, 2 tanh.
template <int BN, int MODE, int BSRC = 0, int IC = 1, int KX = 1, int ST = 1,
          int IW = 1, int OW = 1, int OHW = 1>
__global__ __launch_bounds__(256) void mfma_gemm(
    const void* __restrict__ A, int lda,
    const void* __restrict__ B, int ldb,
    const float* __restrict__ bias,
    bf16* __restrict__ C, int ldc,
    int M, int N, int K, int ACT,
    const int* __restrict__ flagp, int imgBase)
{
    constexpr int BM = 128;
    constexpr int LSTR = 40;                       // bf16 elems per LDS row (80 B)
    __shared__ __align__(16) bf16 As[BM * LSTR];   // 10,240 B
    __shared__ __align__(16) bf16 Bs[BN * LSTR];   // 5,120 / 2,560 B

    const int tid = threadIdx.x;
    const int lane = tid & 63, wave = tid >> 6;
    const int row0 = blockIdx.y * BM, col0 = blockIdx.x * BN;

    // wave tiling: BN=32 -> 4x1 waves of 32x32; BN=64 -> 2x2 waves of 64x32
    constexpr int NWN = (BN >= 64) ? 2 : 1;
    constexpr int WM = BM / (4 / NWN);
    constexpr int WN = BN / NWN;
    constexpr int FM = WM / 16, FN = WN / 16;
    const int wm = (wave / NWN) * WM;
    const int wn = (wave % NWN) * WN;

    fx4 acc[FM][FN] = {};

    // per-thread A staging geometry: 128 rows x 32 k, 16 k per thread
    const int am = tid >> 1;
    const int ak = (tid & 1) * 16;
    const int gm = row0 + am;
    int ibase = 0;
    if constexpr (MODE != 0) {
        int img = imgBase + gm / OHW;
        int s = gm % OHW;
        int oy = s / OW, ox = s % OW;
        ibase = (img * IW + oy * ST) * IW + ox * ST;   // pixel index at ky=kx=0
    }
    const int f32f = (MODE == 1 || BSRC == 1) ? *flagp : 0;

    // per-thread B staging geometry: BN cols x 32 k
    constexpr int KPT = BN / 8;                    // k-values per thread (8 or 4)
    const int nloc = tid & (BN - 1);
    const int kg0 = (tid / BN) * KPT;

    for (int k0 = 0; k0 < K; k0 += 32) {
        // ---- stage A tile ----
        {
            bf16 tb[16];
            const int kk0 = k0 + ak;
            if constexpr (MODE == 0) {
                const unsigned short* Ab = (const unsigned short*)A + (long)gm * lda;
                if (kk0 + 16 <= K) {
                    const unsigned int* s4 = (const unsigned int*)(Ab + kk0);
                    unsigned int* d4 = (unsigned int*)tb;
                    #pragma unroll
                    for (int j = 0; j < 8; ++j) d4[j] = s4[j];
                } else {
                    unsigned short* bs = (unsigned short*)tb;
                    #pragma unroll
                    for (int j = 0; j < 16; ++j) {
                        int kg = kk0 + j;
                        bs[j] = (kg < K) ? Ab[kg] : (unsigned short)0;
                    }
                }
            } else {
                #pragma unroll
                for (int j = 0; j < 16; ++j) {
                    int kg = kk0 + j;
                    int ky = kg / (KX * IC);
                    int rem = kg - ky * (KX * IC);
                    int kx = rem / IC;
                    int ic = rem - kx * IC;
                    long idx = (long)(ibase + ky * IW + kx) * IC + ic;
                    if constexpr (MODE == 1)
                        tb[j] = __float2bfloat16(loadF(A, idx, f32f));
                    else
                        tb[j] = ((const bf16*)A)[idx];
                }
            }
            unsigned int* dst = (unsigned int*)(As + am * LSTR + ak);
            const unsigned int* src = (const unsigned int*)tb;
            #pragma unroll
            for (int j = 0; j < 8; ++j) dst[j] = src[j];
        }
        // ---- stage B tile (transpose to [n][k] in LDS) ----
        {
            bf16 tb[KPT];
            #pragma unroll
            for (int j = 0; j < KPT; ++j) {
                int kg = k0 + kg0 + j;
                if constexpr (BSRC == 1) {
                    float v = 0.f;
                    if (kg < K) v = loadF(B, (long)kg * ldb + col0 + nloc, f32f);
                    tb[j] = __float2bfloat16(v);
                } else {
                    unsigned short v = 0;
                    if (kg < K) v = ((const unsigned short*)B)[(long)kg * ldb + col0 + nloc];
                    ((unsigned short*)tb)[j] = v;
                }
            }
            unsigned int* dst = (unsigned int*)(Bs + nloc * LSTR + kg0);
            const unsigned int* src = (const unsigned int*)tb;
            #pragma unroll
            for (int j = 0; j < KPT / 2; ++j) dst[j] = src[j];
        }
        __syncthreads();

        const int lr = lane & 15, lc = (lane >> 4) * 8;
        s16x8 af[FM], bfr[FN];
        #pragma unroll
        for (int i = 0; i < FM; ++i)
            af[i] = *(const s16x8*)(As + (wm + i * 16 + lr) * LSTR + lc);
        #pragma unroll
        for (int j = 0; j < FN; ++j)
            bfr[j] = *(const s16x8*)(Bs + (wn + j * 16 + lr) * LSTR + lc);
        #pragma unroll
        for (int i = 0; i < FM; ++i)
            #pragma unroll
            for (int j = 0; j < FN; ++j)
                acc[i][j] = __builtin_amdgcn_mfma_f32_16x16x32_bf16(
                    af[i], bfr[j], acc[i][j], 0, 0, 0);
        __syncthreads();
    }

    // epilogue: verified C/D layout col=lane&15, row=(lane>>4)*4+reg
    const int er = (lane >> 4) * 4, ec = lane & 15;
    #pragma unroll
    for (int i = 0; i < FM; ++i) {
        #pragma unroll
        for (int j = 0; j < FN; ++j) {
            const int cc = col0 + wn + j * 16 + ec;
            const float bv = bias[cc];
            #pragma unroll
            for (int r = 0; r < 4; ++r) {
                int rr = row0 + wm + i * 16 + er + r;
                float v = acc[i][j][r] + bv;
                if (ACT == 1) v = fmaxf(v, 0.f);
                if (ACT == 2) v = tanhf(v);
                C[(long)rr * ldc + cc] = __float2bfloat16(v);
            }
        }
    }
}

// ================= concat extras into xin cols 512..517 =================
__global__ __launch_bounds__(256) void concat_k(
    const void* __restrict__ la, const void* __restrict__ lr,
    const void* __restrict__ ct, const void* __restrict__ tte,
    bf16* __restrict__ xin, const int* __restrict__ flagp)
{
    const int f = *flagp;
    int i = blockIdx.x * 256 + threadIdx.x;
    if (i >= 8192 * 6) return;
    int n = i / 6, e = i % 6;
    float v;
    if (e < 3) v = loadF(la, (long)n * 3 + e, f);
    else if (e == 3) v = loadF(lr, n, f);
    else if (e == 4) v = loadF(ct, n, f);
    else v = loadF(tte, n, f);
    xin[(size_t)n * 518 + 512 + e] = __float2bfloat16(v);
}

// ================= persistent cooperative LSTM: 16 steps per launch ======
// 128 blocks x 256 threads (4 waves). Block bk owns 4 h-cols c0=bk*4, i.e.
// 16 gate-cols ordered [i0..i3 | f0..f3 | g0..g3 | o0..o3] as ONE MFMA
// N-tile. whhT fragments (16 k-tiles) live in registers for all 16 steps.
// h recurrence: step gt reads hid row gt-1 (bf16) as A-fragments; c stays
// f32 in registers per thread across steps (global f32 cT at boundaries).
// A/B share the lane->k map (k = kt*32 + 8*(lane>>4) + j) so the mfma's
// internal k-permutation cancels.
__global__ __launch_bounds__(256, 1) void lstm16_k(
    const bf16* __restrict__ zx,     // [2048][2048] chunk (bias pre-added)
    const bf16* __restrict__ whhT,   // [512][2048]
    const int* __restrict__ done,
    const bf16* __restrict__ h0b,    // [128][512]
    bf16* __restrict__ hid,          // [8192][512]
    float* __restrict__ cT,          // [512][128]
    int chunk)
{
    __shared__ float zsm[128][17];
    const int tid = threadIdx.x;
    const int lane = tid & 63, wave = tid >> 6;
    const int bk = blockIdx.x;
    const int c0 = bk * 4;

    const int q = lane & 15;                        // n-tile column
    const int gcol = (q >> 2) * 512 + c0 + (q & 3); // gate-major col in whhT
    const int kb = (lane >> 4) * 8;                 // k offset within 32-tile

    // load B fragments once (whole-launch resident, 64 VGPR)
    s16x8 bfrag[16];
    #pragma unroll
    for (int kt = 0; kt < 16; ++kt) {
        #pragma unroll
        for (int j = 0; j < 8; ++j) {
            int k = kt * 32 + kb + j;
            ((short*)&bfrag[kt])[j] = ((const short*)whhT)[(long)k * 2048 + gcol];
        }
    }

    // c state registers: thread handles p = tid, tid+256 -> b=p>>2, cc=p&3
    float creg[2];
    #pragma unroll
    for (int r = 0; r < 2; ++r) {
        int p = tid + r * 256;
        int b = p >> 2, cc = p & 3;
        creg[r] = cT[(c0 + cc) * 128 + b];
    }

    const int m0 = wave * 32;
    const int lr16 = lane & 15;
    cg::grid_group grid = cg::this_grid();

    for (int ts = 0; ts < 16; ++ts) {
        const int gt = chunk * 16 + ts;
        const bf16* hsrc = (gt == 0) ? h0b : (hid + (long)(gt - 1) * 65536);

        fx4 acc0 = {}, acc1 = {};
        #pragma unroll
        for (int kt = 0; kt < 16; ++kt) {
            s16x8 a0 = *(const s16x8*)(hsrc + (long)(m0 + lr16) * 512 + kt * 32 + kb);
            s16x8 a1 = *(const s16x8*)(hsrc + (long)(m0 + 16 + lr16) * 512 + kt * 32 + kb);
            acc0 = __builtin_amdgcn_mfma_f32_16x16x32_bf16(a0, bfrag[kt], acc0, 0, 0, 0);
            acc1 = __builtin_amdgcn_mfma_f32_16x16x32_bf16(a1, bfrag[kt], acc1, 0, 0, 0);
        }
        // z_hh -> LDS (C/D layout: col=lane&15, row=(lane>>4)*4+r)
        const int er = (lane >> 4) * 4;
        #pragma unroll
        for (int r = 0; r < 4; ++r) zsm[m0 + er + r][q] = acc0[r];
        #pragma unroll
        for (int r = 0; r < 4; ++r) zsm[m0 + 16 + er + r][q] = acc1[r];
        __syncthreads();

        // gate math: 512 (b,cc) pairs, 2 per thread
        #pragma unroll
        for (int r = 0; r < 2; ++r) {
            int p = tid + r * 256;
            int b = p >> 2, cc = p & 3;
            float m = done[gt * 128 + b] ? 0.f : 1.f;
            long zrow = (long)((gt & 15) * 128 + b) * 2048 + c0 + cc;
            float zi = toF(zx[zrow])        + m * zsm[b][0 + cc];
            float zf = toF(zx[zrow + 512])  + m * zsm[b][4 + cc];
            float zg = toF(zx[zrow + 1024]) + m * zsm[b][8 + cc];
            float zo = toF(zx[zrow + 1536]) + m * zsm[b][12 + cc];
            float ig = sigf(zi), fg = sigf(zf), og = sigf(zo);
            float gg = tanhf(zg);
            float cn = fg * (creg[r] * m) + ig * gg;
            float hn = og * tanhf(cn);
            creg[r] = cn;
            hid[(long)(gt * 128 + b) * 512 + c0 + cc] = __float2bfloat16(hn);
        }
        __threadfence();
        grid.sync();
    }

    // write back c for next chunk / final output
    #pragma unroll
    for (int r = 0; r < 2; ++r) {
        int p = tid + r * 256;
        int b = p >> 2, cc = p & 3;
        cT[(c0 + cc) * 128 + b] = creg[r];
    }
}

// ================= actor final =================
__global__ __launch_bounds__(256) void actor_final(
    const bf16* __restrict__ t2, const void* __restrict__ w3,
    const bf16* __restrict__ act, const float* __restrict__ fb,
    void* __restrict__ out, const int* __restrict__ flagp)
{
    const int f = *flagp;
    int lane = threadIdx.x & 63;
    int n = blockIdx.x * 4 + (threadIdx.x >> 6);
    const bf16* row = t2 + (size_t)n * 256;
    float s0 = 0.f, s1 = 0.f, s2 = 0.f;
    #pragma unroll
    for (int j = 0; j < 4; ++j) {
        int k = lane + j * 64;
        float v = toF(row[k]);
        s0 += v * loadF(w3, (long)k * 3 + 0, f);
        s1 += v * loadF(w3, (long)k * 3 + 1, f);
        s2 += v * loadF(w3, (long)k * 3 + 2, f);
    }
    #pragma unroll
    for (int off = 32; off > 0; off >>= 1) {
        s0 += __shfl_down(s0, off, 64);
        s1 += __shfl_down(s1, off, 64);
        s2 += __shfl_down(s2, off, 64);
    }
    if (lane == 0) {
        float mean[3] = {s0 + fb[0], s1 + fb[1], s2 + fb[2]};
        float lp = 0.f, ent = 0.f;
        #pragma unroll
        for (int a = 0; a < 3; ++a) {
            float ls = fb[4 + a];
            float iv = __expf(-2.f * ls);
            float d = toF(act[n * 3 + a]) - mean[a];
            lp += -0.5f * d * d * iv - ls - 0.5f * kLOG2PI;
            ent += 0.5f + 0.5f * kLOG2PI + ls;
        }
        storeOut(out, n, lp, f);
        storeOut(out, 8192 + n, ent, f);
    }
}

// ================= critic final =================
__global__ __launch_bounds__(256) void critic_final(
    const bf16* __restrict__ t2, const void* __restrict__ w3,
    const float* __restrict__ fb, void* __restrict__ out,
    const int* __restrict__ flagp)
{
    const int f = *flagp;
    int lane = threadIdx.x & 63;
    int n = blockIdx.x * 4 + (threadIdx.x >> 6);
    const bf16* row = t2 + (size_t)n * 256;
    float s = 0.f;
    #pragma unroll
    for (int j = 0; j < 4; ++j) {
        int k = lane + j * 64;
        s += toF(row[k]) * loadF(w3, k, f);
    }
    #pragma unroll
    for (int off = 32; off > 0; off >>= 1) s += __shfl_down(s, off, 64);
    if (lane == 0) storeOut(out, 16384 + n, s + fb[3], f);
}

// ================= final state write-out =================
__global__ __launch_bounds__(256) void state_out_k(
    const bf16* __restrict__ hid, const float* __restrict__ cT,
    void* __restrict__ out, const int* __restrict__ flagp)
{
    const int f = *flagp;
    int i = blockIdx.x * 256 + threadIdx.x;   // 65536, i = b*512+k
    if (i >= 65536) return;
    int b = i >> 9, k = i & 511;
    storeOut(out, 24576 + i, toF(hid[4128768 + i]), f);   // row 63*128+b
    storeOut(out, 90112 + i, cT[k * 128 + b], f);
}

extern "C" void kernel_launch(void* const* d_in, const int* in_sizes, int n_in,
                              void* d_out, int out_size, void* d_ws, size_t ws_size,
                              hipStream_t stream)
{
    const void* x        = d_in[0];
    const int*  done     = (const int*)d_in[1];
    const void* last_act = d_in[2];
    const void* last_rew = d_in[3];
    const void* contact  = d_in[4];
    const void* tte      = d_in[5];
    const void* action   = d_in[6];
    const void* h0       = d_in[7];
    const void* c0       = d_in[8];
    const void* conv1_w  = d_in[9],  *conv1_b = d_in[10];
    const void* conv2_w  = d_in[11], *conv2_b = d_in[12];
    const void* conv3_w  = d_in[13], *conv3_b = d_in[14];
    const void* lin_w    = d_in[15], *lin_b   = d_in[16];
    const void* w_ih     = d_in[17], *w_hh    = d_in[18];
    const void* b_ih     = d_in[19], *b_hh    = d_in[20];
    const void* critic_w1 = d_in[21], *critic_b1 = d_in[22];
    const void* critic_w2 = d_in[23], *critic_b2 = d_in[24];
    const void* critic_w3 = d_in[25], *critic_b3 = d_in[26];
    const void* actor_w1  = d_in[27], *actor_b1  = d_in[28];
    const void* actor_w2  = d_in[29], *actor_b2  = d_in[30];
    const void* actor_w3  = d_in[31], *actor_b3  = d_in[32];
    const void* logstd    = d_in[33];

    char* ws = (char*)d_ws;
    bf16*  wihT  = (bf16*)(ws + OFF_WIHT);
    bf16*  whhT  = (bf16*)(ws + OFF_WHHT);
    float* bsum  = (float*)(ws + OFF_BSUM);
    float* linbf = (float*)(ws + OFF_LINB);
    float* hb    = (float*)(ws + OFF_HB);
    float* ab1f = hb + 0, *ab2f = hb + 256, *cb1f = hb + 512, *cb2f = hb + 768;
    bf16*  h0b = (bf16*)(ws + OFF_HT0);
    float* cT  = (float*)(ws + OFF_CT);
    bf16*  cw1 = (bf16*)(ws + OFF_CW1);
    bf16*  cw2 = (bf16*)(ws + OFF_CW2);
    bf16*  cw3 = (bf16*)(ws + OFF_CW3);
    float* cbias = (float*)(ws + OFF_CBIAS);
    bf16*  act = (bf16*)(ws + OFF_ACT);
    float* fb  = (float*)(ws + OFF_FB);
    int*   flagp = (int*)(ws + OFF_FLAG);
    bf16*  xin = (bf16*)(ws + OFF_XIN);
    bf16*  zxb = (bf16*)(ws + OFF_C3H);   // LSTM phase: zx chunk buffer
    bf16*  hid = (bf16*)(ws + OFF_HID);
    bf16*  t1b = (bf16*)(ws + OFF_XIN);   // head phase: xin region
    bf16*  t2b = (bf16*)(ws + OFF_C3H);   // head phase: zx region
    // CNN-phase scratch (c3h/hid regions are dead until the LSTM phase)
    bf16*  out1  = (bf16*)(ws + OFF_OUT1);
    bf16*  out2  = (bf16*)(ws + OFF_OUT2);
    bf16*  out3  = (bf16*)(ws + OFF_OUT3);
    bf16*  linwb = (bf16*)(ws + OFF_LINW);

    // 0) dtype detection
    detect_k<<<1, 64, 0, stream>>>(action, flagp);

    // 1) canonicalize small inputs (+ lin_w -> bf16)
    prep_k<<<11207, 256, 0, stream>>>(w_ih, w_hh, b_ih, b_hh, lin_b,
        actor_b1, actor_b2, critic_b1, critic_b2, h0, c0,
        conv1_w, conv2_w, conv3_w, conv1_b, conv2_b, conv3_b,
        action, actor_b3, critic_b3, logstd,
        wihT, whhT, bsum, linbf, hb, h0b, cT, cw1, cw2, cw3, cbias, act, fb, flagp,
        lin_w, linwb);

    // 2) CNN + linear as MFMA implicit GEMMs, 16 chunks of 512 images
    for (int c = 0; c < 16; ++c) {
        const int ib = c * 512;
        // conv1: 64x64x3 -> 15x15x32, 8x8 s4.  M=512*225, N=32, K=192
        mfma_gemm<32, 1, 0, 3, 8, 4, 64, 15, 225><<<dim3(1, 900), 256, 0, stream>>>(
            x, 0, cw1, 32, cbias, out1, 32, 115200, 32, 192, 1, flagp, ib);
        // conv2: 15x15x32 -> 6x6x64, 4x4 s2.  M=512*36, N=64, K=512
        mfma_gemm<64, 2, 0, 32, 4, 2, 15, 6, 36><<<dim3(1, 144), 256, 0, stream>>>(
            out1, 0, cw2, 64, cbias + 32, out2, 64, 18432, 64, 512, 1, flagp, 0);
        // conv3: 6x6x64 -> 4x4x64, 3x3 s1.  M=512*16, N=64, K=576
        mfma_gemm<64, 2, 0, 64, 3, 1, 6, 4, 16><<<dim3(1, 64), 256, 0, stream>>>(
            out2, 0, cw3, 64, cbias + 96, out3, 64, 8192, 64, 576, 1, flagp, 0);
        // linear: relu(out3 @ lin_w + lin_b) -> xin rows [ib, ib+512)
        mfma_gemm<64, 0><<<dim3(8, 4), 256, 0, stream>>>(
            out3, 1024, linwb, 512, linbf,
            xin + (size_t)ib * 518, 518, 512, 512, 1024, 1, flagp, 0);
    }
    concat_k<<<192, 256, 0, stream>>>(last_act, last_rew, contact, tte, xin, flagp);

    // 3) zx (MFMA) in 4 chunks of 2048 rows + persistent 16-step LSTM each
    for (int chunk = 0; chunk < 4; ++chunk) {
        mfma_gemm<64, 0><<<dim3(32, 16), 256, 0, stream>>>(
            xin + (size_t)chunk * 2048 * 518, 518, wihT, 2048, bsum,
            zxb, 2048, 2048, 2048, 518, 0, flagp, 0);
        {
            const bf16* zxp = zxb;
            const bf16* whp = whhT;
            const int*  dnp = done;
            const bf16* h0p = h0b;
            bf16* hip = hid;
            float* ctp = cT;
            int ck = chunk;
            void* args[] = { (void*)&zxp, (void*)&whp, (void*)&dnp, (void*)&h0p,
                             (void*)&hip, (void*)&ctp, (void*)&ck };
            hipLaunchCooperativeKernel(reinterpret_cast<void*>(lstm16_k),
                                       dim3(128), dim3(256), args, 0, stream);
        }
    }

    // 4) actor head (MFMA, tanh epilogue, dual-dtype B)
    mfma_gemm<64, 0, 1><<<dim3(4, 64), 256, 0, stream>>>(
        hid, 512, actor_w1, 256, ab1f, t1b, 256, 8192, 256, 512, 2, flagp, 0);
    mfma_gemm<64, 0, 1><<<dim3(4, 64), 256, 0, stream>>>(
        t1b, 256, actor_w2, 256, ab2f, t2b, 256, 8192, 256, 256, 2, flagp, 0);
    actor_final<<<2048, 256, 0, stream>>>(t2b, actor_w3, act, fb, d_out, flagp);

    // 5) critic head
    mfma_gemm<64, 0, 1><<<dim3(4, 64), 256, 0, stream>>>(
        hid, 512, critic_w1, 256, cb1f, t1b, 256, 8192, 256, 512, 2, flagp, 0);
    mfma_gemm<64, 0, 1><<<dim3(4, 64), 256, 0, stream>>>(
        t1b, 256, critic_w2, 256, cb2f, t2b, 256, 8192, 256, 256, 2, flagp, 0);
    critic_final<<<2048, 256, 0, stream>>>(t2b, critic_w3, fb, d_out, flagp);

    // 6) hN / cN
    state_out_k<<<256, 256, 0, stream>>>(hid, cT, d_out, flagp);
}

// Round 3
// 5527.334 us; speedup vs baseline: 1.2412x; 1.2412x over previous
//
#include <hip/hip_runtime.h>
#include <hip/hip_bf16.h>
#include <hip/hip_cooperative_groups.h>
#include <cmath>

namespace cg = cooperative_groups;

using bf16 = __hip_bfloat16;

#define DEV static __device__ __forceinline__

DEV float toF(float x) { return x; }
DEV float toF(bf16 x) { return __bfloat162float(x); }

// dual-dtype load: f32==1 -> buffer is float, else bf16
DEV float loadF(const void* p, long i, int f32) {
    return f32 ? ((const float*)p)[i] : toF(((const bf16*)p)[i]);
}
DEV void storeOut(void* out, long i, float v, int f32) {
    if (f32) ((float*)out)[i] = v;
    else ((bf16*)out)[i] = __float2bfloat16(v);
}

__device__ __constant__ float kLOG2PI = 1.8378770664093453f;
DEV float sigf(float x) { return 1.0f / (1.0f + __expf(-x)); }

typedef __attribute__((ext_vector_type(4))) float fx4;
typedef __attribute__((ext_vector_type(8))) short s16x8;   // 8 bf16 (4 VGPR)

// ---------------- workspace layout (bytes), peak 30,485,248 (~29.1 MB) ------
static constexpr size_t OFF_WIHT  = 0;          // bf16 [518][2048]
static constexpr size_t OFF_WHHT  = 2121728;    // bf16 [32][64][512] block-sliced
static constexpr size_t OFF_BSUM  = 4218880;    // f32 2048
static constexpr size_t OFF_LINB  = 4227072;    // f32 512
static constexpr size_t OFF_HB    = 4229120;    // f32 1024
static constexpr size_t OFF_HT0   = 4233216;    // bf16 h0b [128][512] (131072 B used)
static constexpr size_t OFF_HT1   = 4495360;    // (free)
static constexpr size_t OFF_CT    = 4757504;    // f32 [512][128]
static constexpr size_t OFF_CW1   = 5019648;    // bf16 6144
static constexpr size_t OFF_CW2   = 5031936;    // bf16 32768
static constexpr size_t OFF_CW3   = 5097472;    // bf16 36864
static constexpr size_t OFF_CBIAS = 5171200;    // f32 160
static constexpr size_t OFF_ACT   = 5171840;    // bf16 24576
static constexpr size_t OFF_FB    = 5220992;    // f32 8
static constexpr size_t OFF_FLAG  = 5221024;    // int (padded)
static constexpr size_t OFF_XIN   = 5221120;    // bf16 [8192][518] (later t1 bf16)
static constexpr size_t OFF_C3H   = 13708032;   // CNN scratch / zx chunk / t2
static constexpr size_t OFF_HID   = 22096640;   // CNN out1 scratch, then bf16 [8192][512]
// CNN-phase aliases inside the (then unused) C3H / HID regions:
static constexpr size_t OFF_OUT2 = OFF_C3H;               // bf16 [512][6][6][64]  = 2,359,296
static constexpr size_t OFF_OUT3 = OFF_C3H + 2359296;     // bf16 [512][1024]      = 1,048,576
static constexpr size_t OFF_LINW = OFF_C3H + 3407872;     // bf16 [1024][512]      = 1,048,576
static constexpr size_t OFF_OUT1 = OFF_HID;               // bf16 [512][15][15][32]= 7,372,800
// end 30,485,248

// ================= dtype detector =================
__global__ void detect_k(const void* __restrict__ action, int* __restrict__ flag) {
    int lane = threadIdx.x;                        // 64 lanes
    const unsigned short* p = (const unsigned short*)action;
    unsigned short v = p[lane];
    int e = (v >> 7) & 0xFF;                       // bf16 exponent field
    bool bad = (e >= 0x8C);                        // |x| >= 2^13 impossible for N(0,1) bf16
    unsigned long long m = __ballot(bad);
    if (lane == 0) *flag = (m != 0ull) ? 1 : 0;    // bad pattern -> data is f32
}

// ================= prep: canonicalize everything small =================
__global__ __launch_bounds__(256) void prep_k(
    const void* w_ih, const void* w_hh, const void* b_ih, const void* b_hh,
    const void* lin_b, const void* ab1, const void* ab2, const void* cb1, const void* cb2,
    const void* h0, const void* c0,
    const void* c1w, const void* c2w, const void* c3w,
    const void* c1b, const void* c2b, const void* c3b,
    const void* action, const void* ab3, const void* cb3, const void* logstd,
    bf16* __restrict__ wihT, bf16* __restrict__ whhT,
    float* __restrict__ bsum, float* __restrict__ linbf, float* __restrict__ hbias,
    bf16* __restrict__ h0b, float* __restrict__ cT,
    bf16* __restrict__ cw1, bf16* __restrict__ cw2, bf16* __restrict__ cw3,
    float* __restrict__ cbias, bf16* __restrict__ act, float* __restrict__ fb,
    const int* __restrict__ flagp,
    const void* lin_w, bf16* __restrict__ linwb)
{
    const int f = *flagp;
    long i = (long)blockIdx.x * 256 + threadIdx.x;
    if (i < 1060864) { long k = i >> 11, j = i & 2047;
        wihT[i] = __float2bfloat16(loadF(w_ih, j * 518 + k, f)); return; }
    i -= 1060864;
    if (i < 1048576) {
        // block-sliced LSTM weights: whhT[bk][q][k], q in [0,64): gate g=q>>4,
        // h-col = bk*16 + (q&15); global gate col = g*512 + bk*16 + (q&15)
        long bk = i >> 15, q = (i >> 9) & 63, k = i & 511;
        long col = (q >> 4) * 512 + bk * 16 + (q & 15);
        whhT[i] = __float2bfloat16(loadF(w_hh, col * 512 + k, f)); return; }
    i -= 1048576;
    if (i < 2048) { bsum[i] = loadF(b_ih, i, f) + loadF(b_hh, i, f); return; }
    i -= 2048;
    if (i < 512)  { linbf[i] = loadF(lin_b, i, f); return; }
    i -= 512;
    if (i < 1024) { int w = (int)(i >> 8), r = (int)(i & 255);
        const void* s = (w == 0) ? ab1 : (w == 1) ? ab2 : (w == 2) ? cb1 : cb2;
        hbias[i] = loadF(s, r, f); return; }
    i -= 1024;
    if (i < 65536) { h0b[i] = __float2bfloat16(loadF(h0, i, f)); return; }  // [128][512] row-major
    i -= 65536;
    if (i < 65536) { long b = i & 127, k = i >> 7; cT[i]  = loadF(c0, b * 512 + k, f); return; }
    i -= 65536;
    if (i < 6144)  { cw1[i] = __float2bfloat16(loadF(c1w, i, f)); return; }
    i -= 6144;
    if (i < 32768) { cw2[i] = __float2bfloat16(loadF(c2w, i, f)); return; }
    i -= 32768;
    if (i < 36864) { cw3[i] = __float2bfloat16(loadF(c3w, i, f)); return; }
    i -= 36864;
    if (i < 160) { float v = (i < 32) ? loadF(c1b, i, f)
                         : (i < 96) ? loadF(c2b, i - 32, f) : loadF(c3b, i - 96, f);
        cbias[i] = v; return; }
    i -= 160;
    if (i < 24576) { act[i] = __float2bfloat16(loadF(action, i, f)); return; }
    i -= 24576;
    if (i < 8) {
        float v = 0.f;
        if (i < 3) v = loadF(ab3, i, f);
        else if (i == 3) v = loadF(cb3, 0, f);
        else if (i < 7) v = loadF(logstd, i - 4, f);
        fb[i] = v; return;
    }
    i -= 8;
    if (i < 524288) { linwb[i] = __float2bfloat16(loadF(lin_w, i, f)); return; }
}

// ================= MFMA implicit GEMM =================
// C[M][N] = ACT(A @ B + bias), bf16 storage, f32 accum on matrix cores.
// MODE 0: A is plain bf16 row-major [M][lda]. MODE 1: A is conv input (dual
// dtype via flag, NHWC, img offset by imgBase). MODE 2: conv input, bf16.
// BSRC 0: B is bf16 [K][ldb]. BSRC 1: B is dual-dtype raw input via flag.
// ACT: 0 none, 1 relu, 2 tanh.
template <int BN, int MODE, int BSRC = 0, int IC = 1, int KX = 1, int ST = 1,
          int IW = 1, int OW = 1, int OHW = 1>
__global__ __launch_bounds__(256) void mfma_gemm(
    const void* __restrict__ A, int lda,
    const void* __restrict__ B, int ldb,
    const float* __restrict__ bias,
    bf16* __restrict__ C, int ldc,
    int M, int N, int K, int ACT,
    const int* __restrict__ flagp, int imgBase)
{
    constexpr int BM = 128;
    constexpr int LSTR = 40;                       // bf16 elems per LDS row (80 B)
    __shared__ __align__(16) bf16 As[BM * LSTR];   // 10,240 B
    __shared__ __align__(16) bf16 Bs[BN * LSTR];   // 5,120 / 2,560 B

    const int tid = threadIdx.x;
    const int lane = tid & 63, wave = tid >> 6;
    const int row0 = blockIdx.y * BM, col0 = blockIdx.x * BN;

    // wave tiling: BN=32 -> 4x1 waves of 32x32; BN=64 -> 2x2 waves of 64x32
    constexpr int NWN = (BN >= 64) ? 2 : 1;
    constexpr int WM = BM / (4 / NWN);
    constexpr int WN = BN / NWN;
    constexpr int FM = WM / 16, FN = WN / 16;
    const int wm = (wave / NWN) * WM;
    const int wn = (wave % NWN) * WN;

    fx4 acc[FM][FN] = {};

    // per-thread A staging geometry: 128 rows x 32 k, 16 k per thread
    const int am = tid >> 1;
    const int ak = (tid & 1) * 16;
    const int gm = row0 + am;
    int ibase = 0;
    if constexpr (MODE != 0) {
        int img = imgBase + gm / OHW;
        int s = gm % OHW;
        int oy = s / OW, ox = s % OW;
        ibase = (img * IW + oy * ST) * IW + ox * ST;   // pixel index at ky=kx=0
    }
    const int f32f = (MODE == 1 || BSRC == 1) ? *flagp : 0;

    // per-thread B staging geometry: BN cols x 32 k
    constexpr int KPT = BN / 8;                    // k-values per thread (8 or 4)
    const int nloc = tid & (BN - 1);
    const int kg0 = (tid / BN) * KPT;

    for (int k0 = 0; k0 < K; k0 += 32) {
        // ---- stage A tile ----
        {
            bf16 tb[16];
            const int kk0 = k0 + ak;
            if constexpr (MODE == 0) {
                const unsigned short* Ab = (const unsigned short*)A + (long)gm * lda;
                if (kk0 + 16 <= K) {
                    const unsigned int* s4 = (const unsigned int*)(Ab + kk0);
                    unsigned int* d4 = (unsigned int*)tb;
                    #pragma unroll
                    for (int j = 0; j < 8; ++j) d4[j] = s4[j];
                } else {
                    unsigned short* bs = (unsigned short*)tb;
                    #pragma unroll
                    for (int j = 0; j < 16; ++j) {
                        int kg = kk0 + j;
                        bs[j] = (kg < K) ? Ab[kg] : (unsigned short)0;
                    }
                }
            } else {
                #pragma unroll
                for (int j = 0; j < 16; ++j) {
                    int kg = kk0 + j;
                    int ky = kg / (KX * IC);
                    int rem = kg - ky * (KX * IC);
                    int kx = rem / IC;
                    int ic = rem - kx * IC;
                    long idx = (long)(ibase + ky * IW + kx) * IC + ic;
                    if constexpr (MODE == 1)
                        tb[j] = __float2bfloat16(loadF(A, idx, f32f));
                    else
                        tb[j] = ((const bf16*)A)[idx];
                }
            }
            unsigned int* dst = (unsigned int*)(As + am * LSTR + ak);
            const unsigned int* src = (const unsigned int*)tb;
            #pragma unroll
            for (int j = 0; j < 8; ++j) dst[j] = src[j];
        }
        // ---- stage B tile (transpose to [n][k] in LDS) ----
        {
            bf16 tb[KPT];
            #pragma unroll
            for (int j = 0; j < KPT; ++j) {
                int kg = k0 + kg0 + j;
                if constexpr (BSRC == 1) {
                    float v = 0.f;
                    if (kg < K) v = loadF(B, (long)kg * ldb + col0 + nloc, f32f);
                    tb[j] = __float2bfloat16(v);
                } else {
                    unsigned short v = 0;
                    if (kg < K) v = ((const unsigned short*)B)[(long)kg * ldb + col0 + nloc];
                    ((unsigned short*)tb)[j] = v;
                }
            }
            unsigned int* dst = (unsigned int*)(Bs + nloc * LSTR + kg0);
            const unsigned int* src = (const unsigned int*)tb;
            #pragma unroll
            for (int j = 0; j < KPT / 2; ++j) dst[j] = src[j];
        }
        __syncthreads();

        const int lr = lane & 15, lc = (lane >> 4) * 8;
        s16x8 af[FM], bfr[FN];
        #pragma unroll
        for (int i = 0; i < FM; ++i)
            af[i] = *(const s16x8*)(As + (wm + i * 16 + lr) * LSTR + lc);
        #pragma unroll
        for (int j = 0; j < FN; ++j)
            bfr[j] = *(const s16x8*)(Bs + (wn + j * 16 + lr) * LSTR + lc);
        #pragma unroll
        for (int i = 0; i < FM; ++i)
            #pragma unroll
            for (int j = 0; j < FN; ++j)
                acc[i][j] = __builtin_amdgcn_mfma_f32_16x16x32_bf16(
                    af[i], bfr[j], acc[i][j], 0, 0, 0);
        __syncthreads();
    }

    // epilogue: verified C/D layout col=lane&15, row=(lane>>4)*4+reg
    const int er = (lane >> 4) * 4, ec = lane & 15;
    #pragma unroll
    for (int i = 0; i < FM; ++i) {
        #pragma unroll
        for (int j = 0; j < FN; ++j) {
            const int cc = col0 + wn + j * 16 + ec;
            const float bv = bias[cc];
            #pragma unroll
            for (int r = 0; r < 4; ++r) {
                int rr = row0 + wm + i * 16 + er + r;
                float v = acc[i][j][r] + bv;
                if (ACT == 1) v = fmaxf(v, 0.f);
                if (ACT == 2) v = tanhf(v);
                C[(long)rr * ldc + cc] = __float2bfloat16(v);
            }
        }
    }
}

// ================= concat extras into xin cols 512..517 =================
__global__ __launch_bounds__(256) void concat_k(
    const void* __restrict__ la, const void* __restrict__ lr,
    const void* __restrict__ ct, const void* __restrict__ tte,
    bf16* __restrict__ xin, const int* __restrict__ flagp)
{
    const int f = *flagp;
    int i = blockIdx.x * 256 + threadIdx.x;
    if (i >= 8192 * 6) return;
    int n = i / 6, e = i % 6;
    float v;
    if (e < 3) v = loadF(la, (long)n * 3 + e, f);
    else if (e == 3) v = loadF(lr, n, f);
    else if (e == 4) v = loadF(ct, n, f);
    else v = loadF(tte, n, f);
    xin[(size_t)n * 518 + 512 + e] = __float2bfloat16(v);
}

// ================= persistent cooperative LSTM: 16 steps per launch ======
// 32 blocks x 256 threads (4 waves). Block bk owns 16 h-cols hc0=bk*16,
// i.e. 64 gate-cols = 4 MFMA n-tiles ordered [i|f|g|o]. The 64x512 W_hh
// slice (64 KB) is staged into LDS once per launch and is step-invariant.
// Per step: each wave computes z_hh for its 32 batch rows x 64 gate cols
// (2 m-tiles x 4 n-tiles x 16 k-tiles = 128 mfma). The C/D layout puts all
// 4 gates of h-col hc in the SAME lane (acc[mt][g][r]) -> gate math is
// fully thread-local; c-state lives in 8 registers across all steps.
// One threadfence+grid.sync per step publishes the 128x512 h row.
__global__ __launch_bounds__(256, 1) void lstm16_k(
    const bf16* __restrict__ zx,     // [2048][2048] chunk (bias pre-added)
    const bf16* __restrict__ whhB,   // [32][64][512] block-sliced
    const int* __restrict__ done,
    const bf16* __restrict__ h0b,    // [128][512]
    bf16* __restrict__ hid,          // [8192][512]
    float* __restrict__ cT,          // [512][128]
    int chunk)
{
    constexpr int LP = 520;                        // padded k-stride (2-way banks)
    __shared__ __align__(16) bf16 Bs[64 * LP];     // 66,560 B
    const int tid = threadIdx.x;
    const int lane = tid & 63, wave = tid >> 6;
    const int bk = blockIdx.x;
    const int lr16 = lane & 15;
    const int kb = (lane >> 4) * 8;
    const int er = (lane >> 4) * 4;
    const int hc = bk * 16 + lr16;                 // this thread's h-col
    const int m0 = wave * 32;

    // stage the 64x512 weight slice: whhB[bk*32768 + q*512 + k] -> Bs[q*LP + k]
    {
        const s16x8* src = (const s16x8*)(whhB + (long)bk * 32768);
        #pragma unroll
        for (int it = 0; it < 16; ++it) {
            int idx = it * 256 + tid;              // chunk of 8 bf16
            int q = idx >> 6, k8 = (idx & 63) * 8;
            *(s16x8*)(Bs + q * LP + k8) = src[idx];
        }
    }

    // c-state: creg[mt][r] for b = m0 + mt*16 + er + r, col hc
    float creg[2][4];
    #pragma unroll
    for (int mt = 0; mt < 2; ++mt)
        #pragma unroll
        for (int r = 0; r < 4; ++r)
            creg[mt][r] = cT[(long)hc * 128 + (m0 + mt * 16 + er + r)];

    __syncthreads();
    cg::grid_group grid = cg::this_grid();

    for (int ts = 0; ts < 16; ++ts) {
        const int gt = chunk * 16 + ts;
        const bf16* hsrc = (gt == 0) ? h0b : (hid + (long)(gt - 1) * 65536);

        fx4 acc[2][4] = {};
        #pragma unroll
        for (int kt = 0; kt < 16; ++kt) {
            s16x8 a0 = *(const s16x8*)(hsrc + (long)(m0 + lr16) * 512 + kt * 32 + kb);
            s16x8 a1 = *(const s16x8*)(hsrc + (long)(m0 + 16 + lr16) * 512 + kt * 32 + kb);
            #pragma unroll
            for (int g = 0; g < 4; ++g) {
                s16x8 bf = *(const s16x8*)(Bs + (g * 16 + lr16) * LP + kt * 32 + kb);
                acc[0][g] = __builtin_amdgcn_mfma_f32_16x16x32_bf16(a0, bf, acc[0][g], 0, 0, 0);
                acc[1][g] = __builtin_amdgcn_mfma_f32_16x16x32_bf16(a1, bf, acc[1][g], 0, 0, 0);
            }
        }

        // gate math (thread-local) + h write
        #pragma unroll
        for (int mt = 0; mt < 2; ++mt) {
            #pragma unroll
            for (int r = 0; r < 4; ++r) {
                const int b = m0 + mt * 16 + er + r;
                const float m = done[gt * 128 + b] ? 0.f : 1.f;
                const long zr = (long)((gt & 15) * 128 + b) * 2048 + hc;
                float zi = toF(zx[zr])        + m * acc[mt][0][r];
                float zf = toF(zx[zr + 512])  + m * acc[mt][1][r];
                float zg = toF(zx[zr + 1024]) + m * acc[mt][2][r];
                float zo = toF(zx[zr + 1536]) + m * acc[mt][3][r];
                float ig = sigf(zi), fg = sigf(zf), og = sigf(zo);
                float gg = tanhf(zg);
                float cn = fg * (creg[mt][r] * m) + ig * gg;
                float hn = og * tanhf(cn);
                creg[mt][r] = cn;
                hid[(long)(gt * 128 + b) * 512 + hc] = __float2bfloat16(hn);
            }
        }
        __threadfence();
        grid.sync();
    }

    // write back c for next chunk / final output
    #pragma unroll
    for (int mt = 0; mt < 2; ++mt)
        #pragma unroll
        for (int r = 0; r < 4; ++r)
            cT[(long)hc * 128 + (m0 + mt * 16 + er + r)] = creg[mt][r];
}

// ================= actor final =================
__global__ __launch_bounds__(256) void actor_final(
    const bf16* __restrict__ t2, const void* __restrict__ w3,
    const bf16* __restrict__ act, const float* __restrict__ fb,
    void* __restrict__ out, const int* __restrict__ flagp)
{
    const int f = *flagp;
    int lane = threadIdx.x & 63;
    int n = blockIdx.x * 4 + (threadIdx.x >> 6);
    const bf16* row = t2 + (size_t)n * 256;
    float s0 = 0.f, s1 = 0.f, s2 = 0.f;
    #pragma unroll
    for (int j = 0; j < 4; ++j) {
        int k = lane + j * 64;
        float v = toF(row[k]);
        s0 += v * loadF(w3, (long)k * 3 + 0, f);
        s1 += v * loadF(w3, (long)k * 3 + 1, f);
        s2 += v * loadF(w3, (long)k * 3 + 2, f);
    }
    #pragma unroll
    for (int off = 32; off > 0; off >>= 1) {
        s0 += __shfl_down(s0, off, 64);
        s1 += __shfl_down(s1, off, 64);
        s2 += __shfl_down(s2, off, 64);
    }
    if (lane == 0) {
        float mean[3] = {s0 + fb[0], s1 + fb[1], s2 + fb[2]};
        float lp = 0.f, ent = 0.f;
        #pragma unroll
        for (int a = 0; a < 3; ++a) {
            float ls = fb[4 + a];
            float iv = __expf(-2.f * ls);
            float d = toF(act[n * 3 + a]) - mean[a];
            lp += -0.5f * d * d * iv - ls - 0.5f * kLOG2PI;
            ent += 0.5f + 0.5f * kLOG2PI + ls;
        }
        storeOut(out, n, lp, f);
        storeOut(out, 8192 + n, ent, f);
    }
}

// ================= critic final =================
__global__ __launch_bounds__(256) void critic_final(
    const bf16* __restrict__ t2, const void* __restrict__ w3,
    const float* __restrict__ fb, void* __restrict__ out,
    const int* __restrict__ flagp)
{
    const int f = *flagp;
    int lane = threadIdx.x & 63;
    int n = blockIdx.x * 4 + (threadIdx.x >> 6);
    const bf16* row = t2 + (size_t)n * 256;
    float s = 0.f;
    #pragma unroll
    for (int j = 0; j < 4; ++j) {
        int k = lane + j * 64;
        s += toF(row[k]) * loadF(w3, k, f);
    }
    #pragma unroll
    for (int off = 32; off > 0; off >>= 1) s += __shfl_down(s, off, 64);
    if (lane == 0) storeOut(out, 16384 + n, s + fb[3], f);
}

// ================= final state write-out =================
__global__ __launch_bounds__(256) void state_out_k(
    const bf16* __restrict__ hid, const float* __restrict__ cT,
    void* __restrict__ out, const int* __restrict__ flagp)
{
    const int f = *flagp;
    int i = blockIdx.x * 256 + threadIdx.x;   // 65536, i = b*512+k
    if (i >= 65536) return;
    int b = i >> 9, k = i & 511;
    storeOut(out, 24576 + i, toF(hid[4128768 + i]), f);   // row 63*128+b
    storeOut(out, 90112 + i, cT[k * 128 + b], f);
}

extern "C" void kernel_launch(void* const* d_in, const int* in_sizes, int n_in,
                              void* d_out, int out_size, void* d_ws, size_t ws_size,
                              hipStream_t stream)
{
    const void* x        = d_in[0];
    const int*  done     = (const int*)d_in[1];
    const void* last_act = d_in[2];
    const void* last_rew = d_in[3];
    const void* contact  = d_in[4];
    const void* tte      = d_in[5];
    const void* action   = d_in[6];
    const void* h0       = d_in[7];
    const void* c0       = d_in[8];
    const void* conv1_w  = d_in[9],  *conv1_b = d_in[10];
    const void* conv2_w  = d_in[11], *conv2_b = d_in[12];
    const void* conv3_w  = d_in[13], *conv3_b = d_in[14];
    const void* lin_w    = d_in[15], *lin_b   = d_in[16];
    const void* w_ih     = d_in[17], *w_hh    = d_in[18];
    const void* b_ih     = d_in[19], *b_hh    = d_in[20];
    const void* critic_w1 = d_in[21], *critic_b1 = d_in[22];
    const void* critic_w2 = d_in[23], *critic_b2 = d_in[24];
    const void* critic_w3 = d_in[25], *critic_b3 = d_in[26];
    const void* actor_w1  = d_in[27], *actor_b1  = d_in[28];
    const void* actor_w2  = d_in[29], *actor_b2  = d_in[30];
    const void* actor_w3  = d_in[31], *actor_b3  = d_in[32];
    const void* logstd    = d_in[33];

    char* ws = (char*)d_ws;
    bf16*  wihT  = (bf16*)(ws + OFF_WIHT);
    bf16*  whhT  = (bf16*)(ws + OFF_WHHT);
    float* bsum  = (float*)(ws + OFF_BSUM);
    float* linbf = (float*)(ws + OFF_LINB);
    float* hb    = (float*)(ws + OFF_HB);
    float* ab1f = hb + 0, *ab2f = hb + 256, *cb1f = hb + 512, *cb2f = hb + 768;
    bf16*  h0b = (bf16*)(ws + OFF_HT0);
    float* cT  = (float*)(ws + OFF_CT);
    bf16*  cw1 = (bf16*)(ws + OFF_CW1);
    bf16*  cw2 = (bf16*)(ws + OFF_CW2);
    bf16*  cw3 = (bf16*)(ws + OFF_CW3);
    float* cbias = (float*)(ws + OFF_CBIAS);
    bf16*  act = (bf16*)(ws + OFF_ACT);
    float* fb  = (float*)(ws + OFF_FB);
    int*   flagp = (int*)(ws + OFF_FLAG);
    bf16*  xin = (bf16*)(ws + OFF_XIN);
    bf16*  zxb = (bf16*)(ws + OFF_C3H);   // LSTM phase: zx chunk buffer
    bf16*  hid = (bf16*)(ws + OFF_HID);
    bf16*  t1b = (bf16*)(ws + OFF_XIN);   // head phase: xin region
    bf16*  t2b = (bf16*)(ws + OFF_C3H);   // head phase: zx region
    // CNN-phase scratch (c3h/hid regions are dead until the LSTM phase)
    bf16*  out1  = (bf16*)(ws + OFF_OUT1);
    bf16*  out2  = (bf16*)(ws + OFF_OUT2);
    bf16*  out3  = (bf16*)(ws + OFF_OUT3);
    bf16*  linwb = (bf16*)(ws + OFF_LINW);

    // 0) dtype detection
    detect_k<<<1, 64, 0, stream>>>(action, flagp);

    // 1) canonicalize small inputs (+ lin_w -> bf16)
    prep_k<<<11207, 256, 0, stream>>>(w_ih, w_hh, b_ih, b_hh, lin_b,
        actor_b1, actor_b2, critic_b1, critic_b2, h0, c0,
        conv1_w, conv2_w, conv3_w, conv1_b, conv2_b, conv3_b,
        action, actor_b3, critic_b3, logstd,
        wihT, whhT, bsum, linbf, hb, h0b, cT, cw1, cw2, cw3, cbias, act, fb, flagp,
        lin_w, linwb);

    // 2) CNN + linear as MFMA implicit GEMMs, 16 chunks of 512 images
    for (int c = 0; c < 16; ++c) {
        const int ib = c * 512;
        // conv1: 64x64x3 -> 15x15x32, 8x8 s4.  M=512*225, N=32, K=192
        mfma_gemm<32, 1, 0, 3, 8, 4, 64, 15, 225><<<dim3(1, 900), 256, 0, stream>>>(
            x, 0, cw1, 32, cbias, out1, 32, 115200, 32, 192, 1, flagp, ib);
        // conv2: 15x15x32 -> 6x6x64, 4x4 s2.  M=512*36, N=64, K=512
        mfma_gemm<64, 2, 0, 32, 4, 2, 15, 6, 36><<<dim3(1, 144), 256, 0, stream>>>(
            out1, 0, cw2, 64, cbias + 32, out2, 64, 18432, 64, 512, 1, flagp, 0);
        // conv3: 6x6x64 -> 4x4x64, 3x3 s1.  M=512*16, N=64, K=576
        mfma_gemm<64, 2, 0, 64, 3, 1, 6, 4, 16><<<dim3(1, 64), 256, 0, stream>>>(
            out2, 0, cw3, 64, cbias + 96, out3, 64, 8192, 64, 576, 1, flagp, 0);
        // linear: relu(out3 @ lin_w + lin_b) -> xin rows [ib, ib+512)
        mfma_gemm<64, 0><<<dim3(8, 4), 256, 0, stream>>>(
            out3, 1024, linwb, 512, linbf,
            xin + (size_t)ib * 518, 518, 512, 512, 1024, 1, flagp, 0);
    }
    concat_k<<<192, 256, 0, stream>>>(last_act, last_rew, contact, tte, xin, flagp);

    // 3) zx (MFMA) in 4 chunks of 2048 rows + persistent 16-step LSTM each
    for (int chunk = 0; chunk < 4; ++chunk) {
        mfma_gemm<64, 0><<<dim3(32, 16), 256, 0, stream>>>(
            xin + (size_t)chunk * 2048 * 518, 518, wihT, 2048, bsum,
            zxb, 2048, 2048, 2048, 518, 0, flagp, 0);
        {
            const bf16* zxp = zxb;
            const bf16* whp = whhT;
            const int*  dnp = done;
            const bf16* h0p = h0b;
            bf16* hip = hid;
            float* ctp = cT;
            int ck = chunk;
            void* args[] = { (void*)&zxp, (void*)&whp, (void*)&dnp, (void*)&h0p,
                             (void*)&hip, (void*)&ctp, (void*)&ck };
            hipLaunchCooperativeKernel(reinterpret_cast<void*>(lstm16_k),
                                       dim3(32), dim3(256), args, 0, stream);
        }
    }

    // 4) actor head (MFMA, tanh epilogue, dual-dtype B)
    mfma_gemm<64, 0, 1><<<dim3(4, 64), 256, 0, stream>>>(
        hid, 512, actor_w1, 256, ab1f, t1b, 256, 8192, 256, 512, 2, flagp, 0);
    mfma_gemm<64, 0, 1><<<dim3(4, 64), 256, 0, stream>>>(
        t1b, 256, actor_w2, 256, ab2f, t2b, 256, 8192, 256, 256, 2, flagp, 0);
    actor_final<<<2048, 256, 0, stream>>>(t2b, actor_w3, act, fb, d_out, flagp);

    // 5) critic head
    mfma_gemm<64, 0, 1><<<dim3(4, 64), 256, 0, stream>>>(
        hid, 512, critic_w1, 256, cb1f, t1b, 256, 8192, 256, 512, 2, flagp, 0);
    mfma_gemm<64, 0, 1><<<dim3(4, 64), 256, 0, stream>>>(
        t1b, 256, critic_w2, 256, cb2f, t2b, 256, 8192, 256, 256, 2, flagp, 0);
    critic_final<<<2048, 256, 0, stream>>>(t2b, critic_w3, fb, d_out, flagp);

    // 6) hN / cN
    state_out_k<<<256, 256, 0, stream>>>(hid, cT, d_out, flagp);
}